// Round 1
// baseline (132.803 us; speedup 1.0000x reference)
//
#include <hip/hip_runtime.h>

#define V 22
#define NB 32
#define NS 512
#define ND 512
#define NF 2048
#define M_TOT (NB * V)   // 704 distinct (batch, token) rows

#define BM 32
#define BF 128
#define BK 64

// ---------------- Kernel A: count digit tokens (ids 13..21) over s in [0,510] ----------------
__global__ void count_digits(const int* __restrict__ tokens, int* __restrict__ n_dig) {
    int b = blockIdx.x;
    int tid = threadIdx.x;
    int cnt = 0;
    for (int s = tid; s < NS - 1; s += blockDim.x) {
        int t = tokens[b * NS + s];
        cnt += (t >= 13 && t <= 21) ? 1 : 0;
    }
    // wave64 reduce
    for (int off = 32; off > 0; off >>= 1) cnt += __shfl_down(cnt, off, 64);
    __shared__ int wsum[4];
    int wave = tid >> 6, lane = tid & 63;
    if (lane == 0) wsum[wave] = cnt;
    __syncthreads();
    if (tid == 0) {
        int tot = 0;
        for (int w = 0; w < (int)(blockDim.x >> 6); ++w) tot += wsum[w];
        n_dig[b] = tot;
    }
}

// ---------------- Kernel B-init: lt[m][v] = b2[v] ----------------
__global__ void init_lt(float* __restrict__ lt, const float* __restrict__ b2) {
    int i = blockIdx.x * blockDim.x + threadIdx.x;
    if (i < M_TOT * V) lt[i] = b2[i % V];
}

// ---------------- Kernel B: fused (emb[t]+z[b]) @ W1 -> relu -> @ W2, atomically into lt ----------------
// grid: (22 m-tiles, 16 f-chunks), 256 threads
__global__ __launch_bounds__(256) void fused_gemm(
    const float* __restrict__ emb, const float* __restrict__ z,
    const float* __restrict__ W1, const float* __restrict__ b1,
    const float* __restrict__ W2, float* __restrict__ lt)
{
    __shared__ float xs[BM][BK + 4];   // 32 x 68 fp32
    __shared__ float w1s[BK][BF];      // 64 x 128 fp32
    __shared__ float hs[BM][BF];       // 32 x 128 fp32

    const int tileM = blockIdx.x;      // 0..21
    const int tileF = blockIdx.y;      // 0..15
    const int m0 = tileM * BM;
    const int f0 = tileF * BF;
    const int tid = threadIdx.x;

    const int ty = tid >> 5;           // 0..7  -> 4 rows each
    const int tx = tid & 31;           // 0..31 -> 4 cols each

    float acc[4][4] = {};

    // x-staging mapping: thread loads 8 consecutive k for one row
    const int lrow = tid >> 3;             // 0..31
    const int lcol = (tid & 7) * 8;        // 0..56
    const int m = m0 + lrow;
    const int bb = m / V;
    const int tt = m - bb * V;
    const float* __restrict__ embrow = emb + tt * ND;
    const float* __restrict__ zrow   = z   + bb * ND;

    for (int k0 = 0; k0 < ND; k0 += BK) {
        // stage x tile (32 x 64)
        #pragma unroll
        for (int e = 0; e < 8; ++e) {
            int k = k0 + lcol + e;
            xs[lrow][lcol + e] = embrow[k] + zrow[k];
        }
        // stage W1 tile (64 x 128) as float4: 2048 float4 / 256 threads = 8 each
        #pragma unroll
        for (int it = 0; it < 8; ++it) {
            int e4 = it * 256 + tid;          // float4 index
            int r = e4 >> 5;                  // 32 float4 per row
            int c = (e4 & 31) << 2;
            *(float4*)&w1s[r][c] = *(const float4*)&W1[(size_t)(k0 + r) * NF + f0 + c];
        }
        __syncthreads();

        #pragma unroll
        for (int kk = 0; kk < BK; ++kk) {
            float a0 = xs[ty * 4 + 0][kk];
            float a1 = xs[ty * 4 + 1][kk];
            float a2 = xs[ty * 4 + 2][kk];
            float a3 = xs[ty * 4 + 3][kk];
            float4 bv = *(float4*)&w1s[kk][tx * 4];
            acc[0][0] = fmaf(a0, bv.x, acc[0][0]);
            acc[0][1] = fmaf(a0, bv.y, acc[0][1]);
            acc[0][2] = fmaf(a0, bv.z, acc[0][2]);
            acc[0][3] = fmaf(a0, bv.w, acc[0][3]);
            acc[1][0] = fmaf(a1, bv.x, acc[1][0]);
            acc[1][1] = fmaf(a1, bv.y, acc[1][1]);
            acc[1][2] = fmaf(a1, bv.z, acc[1][2]);
            acc[1][3] = fmaf(a1, bv.w, acc[1][3]);
            acc[2][0] = fmaf(a2, bv.x, acc[2][0]);
            acc[2][1] = fmaf(a2, bv.y, acc[2][1]);
            acc[2][2] = fmaf(a2, bv.z, acc[2][2]);
            acc[2][3] = fmaf(a2, bv.w, acc[2][3]);
            acc[3][0] = fmaf(a3, bv.x, acc[3][0]);
            acc[3][1] = fmaf(a3, bv.y, acc[3][1]);
            acc[3][2] = fmaf(a3, bv.z, acc[3][2]);
            acc[3][3] = fmaf(a3, bv.w, acc[3][3]);
        }
        __syncthreads();
    }

    // h = relu(acc + b1), into LDS
    {
        float4 bias = *(const float4*)&b1[f0 + tx * 4];
        #pragma unroll
        for (int i = 0; i < 4; ++i) {
            float4 hv;
            hv.x = fmaxf(acc[i][0] + bias.x, 0.f);
            hv.y = fmaxf(acc[i][1] + bias.y, 0.f);
            hv.z = fmaxf(acc[i][2] + bias.z, 0.f);
            hv.w = fmaxf(acc[i][3] + bias.w, 0.f);
            *(float4*)&hs[ty * 4 + i][tx * 4] = hv;
        }
    }
    __syncthreads();

    // stage 2: logits partial = hs(32x128) @ W2[f0:f0+128, 0:22], atomic into lt
    for (int o = tid; o < BM * V; o += 256) {
        int r = o / V;
        int v = o - r * V;
        float s0 = 0.f, s1 = 0.f;
        #pragma unroll 8
        for (int c = 0; c < BF; c += 2) {
            s0 = fmaf(hs[r][c],     W2[(size_t)(f0 + c)     * V + v], s0);
            s1 = fmaf(hs[r][c + 1], W2[(size_t)(f0 + c + 1) * V + v], s1);
        }
        atomicAdd(&lt[(m0 + r) * V + v], s0 + s1);
    }
}

// ---------------- Kernel C: scatter to output with constraint mask ----------------
// D_DIGIT bitmask (ids 0,1,2,13..21) = 0x3FE007 ; D_NONDIGIT (ids 0,1,2,12) = 0x001007
__global__ void scatter_out(const int* __restrict__ tokens, const float* __restrict__ lt,
                            const int* __restrict__ n_dig, float* __restrict__ out) {
    int idx = blockIdx.x * blockDim.x + threadIdx.x;
    if (idx >= NB * NS * V) return;
    int v  = idx % V;
    int bs = idx / V;
    int s  = bs % NS;
    int b  = bs / NS;
    int tok = tokens[b * NS + s];
    float nd = (float)n_dig[b];
    float nn = (float)(NS - 1) - nd;
    float dd = ((0x3FE007 >> v) & 1) ? 1.f : 0.f;
    float dn = ((0x001007 >> v) & 1) ? 1.f : 0.f;
    float mask = nd * dd + nn * dn;
    out[idx] = lt[(b * V + tok) * V + v] - 0.5f * mask;
}

extern "C" void kernel_launch(void* const* d_in, const int* in_sizes, int n_in,
                              void* d_out, int out_size, void* d_ws, size_t ws_size,
                              hipStream_t stream) {
    const int*   tokens = (const int*)d_in[0];
    const float* z      = (const float*)d_in[1];
    const float* emb    = (const float*)d_in[2];
    const float* W1     = (const float*)d_in[3];
    const float* b1     = (const float*)d_in[4];
    const float* W2     = (const float*)d_in[5];
    const float* b2     = (const float*)d_in[6];
    float* out = (float*)d_out;

    float* lt    = (float*)d_ws;                                    // 704*22 fp32
    int*   n_dig = (int*)((char*)d_ws + M_TOT * V * sizeof(float)); // 32 ints

    count_digits<<<NB, 256, 0, stream>>>(tokens, n_dig);
    init_lt<<<(M_TOT * V + 255) / 256, 256, 0, stream>>>(lt, b2);
    fused_gemm<<<dim3(22, 16), 256, 0, stream>>>(emb, z, W1, b1, W2, lt);
    scatter_out<<<(NB * NS * V + 255) / 256, 256, 0, stream>>>(tokens, lt, n_dig, out);
}

// Round 2
// 87.074 us; speedup vs baseline: 1.5252x; 1.5252x over previous
//
#include <hip/hip_runtime.h>

#define V 22
#define NB 32
#define NS 512
#define ND 512
#define NF 2048
#define M_TOT 704   // NB * V distinct (batch, token) rows

typedef __attribute__((ext_vector_type(8))) short bf16x8;
typedef __attribute__((ext_vector_type(4))) float f32x4;
typedef unsigned short ushort_t;

__device__ __forceinline__ unsigned short f2bf(float f) {
    unsigned u = __float_as_uint(f);
    u += 0x7FFFu + ((u >> 16) & 1u);
    return (unsigned short)(u >> 16);
}

// =============== K1: prep — W1 transpose->bf16, X build, digit count, lt init ===============
// grid: [0,256) W1T tiles, [256,432) X, [432,464) count, [464,525) lt init
__global__ __launch_bounds__(256) void prep_kernel(
    const int* __restrict__ tokens, const float* __restrict__ z,
    const float* __restrict__ emb, const float* __restrict__ W1,
    const float* __restrict__ b2,
    ushort_t* __restrict__ W1T, ushort_t* __restrict__ X,
    float* __restrict__ lt, int* __restrict__ n_dig)
{
    __shared__ __align__(16) unsigned short T[64 * 72];
    __shared__ int wsum[4];
    const int bid = blockIdx.x, tid = threadIdx.x;

    if (bid < 256) {
        // transpose 64(k) x 64(f) tile of W1 -> W1T[f][k] bf16
        const int k0 = (bid >> 5) * 64, f0 = (bid & 31) * 64;
        #pragma unroll
        for (int rep = 0; rep < 4; ++rep) {
            int k = rep * 16 + (tid >> 4);
            int f = (tid & 15) * 4;
            float4 v = *(const float4*)&W1[(size_t)(k0 + k) * NF + f0 + f];
            T[(f + 0) * 72 + k] = f2bf(v.x);
            T[(f + 1) * 72 + k] = f2bf(v.y);
            T[(f + 2) * 72 + k] = f2bf(v.z);
            T[(f + 3) * 72 + k] = f2bf(v.w);
        }
        __syncthreads();
        #pragma unroll
        for (int rep = 0; rep < 2; ++rep) {
            int fr = rep * 32 + (tid >> 3);
            int kc = (tid & 7) * 8;
            int4 v = *(const int4*)&T[fr * 72 + kc];
            *(int4*)&W1T[(size_t)(f0 + fr) * ND + k0 + kc] = v;
        }
    } else if (bid < 432) {
        // X[m][k] = bf16(emb[tok][k] + z[b][k]); block covers 4 m-rows
        const int g = bid - 256;
        const int r = tid >> 6;
        const int kk = (tid & 63) * 8;
        const int m = g * 4 + r;
        const int b = m / V;
        const int t = m - b * V;
        const float* er = emb + (size_t)t * ND + kk;
        const float* zr = z + (size_t)b * ND + kk;
        ushort_t o[8];
        #pragma unroll
        for (int e = 0; e < 8; ++e) o[e] = f2bf(er[e] + zr[e]);
        *(int4*)&X[(size_t)m * ND + kk] = *(int4*)o;
    } else if (bid < 464) {
        const int b = bid - 432;
        int cnt = 0;
        for (int s = tid; s < NS - 1; s += 256) {
            int t = tokens[b * NS + s];
            cnt += (t >= 13 && t <= 21);
        }
        for (int off = 32; off > 0; off >>= 1) cnt += __shfl_down(cnt, off, 64);
        if ((tid & 63) == 0) wsum[tid >> 6] = cnt;
        __syncthreads();
        if (tid == 0) n_dig[b] = wsum[0] + wsum[1] + wsum[2] + wsum[3];
    } else {
        const int i = (bid - 464) * 256 + tid;
        if (i < M_TOT * V) lt[i] = b2[i % V];
    }
}

// =============== K2: MFMA GEMM1 (relu) + fused GEMM2 partial -> atomic lt ===============
// block tile: 32(m) x 64(f), K-step 128, 4 waves (2m x 2n), wave tile 16x32
// LDS: dbuf { A 32x256B swz (8KB) + B 64x256B swz (16KB) } x2 = 48KB
__global__ __launch_bounds__(256) void gemm_fused(
    const ushort_t* __restrict__ X, const ushort_t* __restrict__ W1T,
    const float* __restrict__ b1, const float* __restrict__ W2,
    float* __restrict__ lt)
{
    __shared__ __align__(16) char smem[49152];
    const int tid = threadIdx.x;
    const int m0 = blockIdx.x * 32;
    const int f0 = blockIdx.y * 64;
    const int lane = tid & 63;
    const int wave = tid >> 6;
    const int wm = wave >> 1, wn = wave & 1;

    // staging addressing: 16 lanes cover one full 256B row; XOR-swizzle on LDS write
    const int srow = tid >> 4;                 // 0..15 (+16/32/48 reps)
    const int sphys = ((tid & 15) * 16) ^ ((srow & 7) << 4);
    const ushort_t* gA = X + (size_t)(m0 + srow) * ND + (tid & 15) * 8;
    const ushort_t* gB = W1T + (size_t)(f0 + srow) * ND + (tid & 15) * 8;

    // mfma fragment read addressing (same XOR on read)
    const int swr = (lane & 7) << 4;
    const int rowA = wm * 16 + (lane & 15);
    const int rowB = wn * 32 + (lane & 15);
    const int kgrp = (lane >> 4) * 16;         // byte offset of lane's 8-elem k-group

    int4 ra0, ra1, rb0, rb1, rb2, rb3;
    f32x4 acc[2];
    acc[0] = (f32x4){0.f, 0.f, 0.f, 0.f};
    acc[1] = (f32x4){0.f, 0.f, 0.f, 0.f};

#define LOADT(kt) { \
    ra0 = *(const int4*)(gA + (kt) * 128); \
    ra1 = *(const int4*)(gA + (kt) * 128 + 16 * ND); \
    rb0 = *(const int4*)(gB + (kt) * 128); \
    rb1 = *(const int4*)(gB + (kt) * 128 + 16 * ND); \
    rb2 = *(const int4*)(gB + (kt) * 128 + 32 * ND); \
    rb3 = *(const int4*)(gB + (kt) * 128 + 48 * ND); }

#define WRITET(bufi) { \
    char* Ab = smem + (bufi) * 24576; \
    char* Bb = Ab + 8192; \
    *(int4*)(Ab + srow * 256 + sphys) = ra0; \
    *(int4*)(Ab + (srow + 16) * 256 + sphys) = ra1; \
    *(int4*)(Bb + srow * 256 + sphys) = rb0; \
    *(int4*)(Bb + (srow + 16) * 256 + sphys) = rb1; \
    *(int4*)(Bb + (srow + 32) * 256 + sphys) = rb2; \
    *(int4*)(Bb + (srow + 48) * 256 + sphys) = rb3; }

#define COMPUTET(bufi) { \
    const char* Ab = smem + (bufi) * 24576; \
    const char* Bb = Ab + 8192; \
    _Pragma("unroll") \
    for (int ks = 0; ks < 4; ++ks) { \
        int kb = ks * 64 + kgrp; \
        bf16x8 af  = *(const bf16x8*)(Ab + rowA * 256 + (kb ^ swr)); \
        bf16x8 bf0 = *(const bf16x8*)(Bb + rowB * 256 + (kb ^ swr)); \
        bf16x8 bf1 = *(const bf16x8*)(Bb + (rowB + 16) * 256 + (kb ^ swr)); \
        acc[0] = __builtin_amdgcn_mfma_f32_16x16x32_bf16(af, bf0, acc[0], 0, 0, 0); \
        acc[1] = __builtin_amdgcn_mfma_f32_16x16x32_bf16(af, bf1, acc[1], 0, 0, 0); \
    } }

    LOADT(0);              WRITET(0); __syncthreads();
    LOADT(1); COMPUTET(0); WRITET(1); __syncthreads();
    LOADT(2); COMPUTET(1); WRITET(0); __syncthreads();
    LOADT(3); COMPUTET(0); WRITET(1); __syncthreads();
              COMPUTET(1);

    // ---- epilogue: bias+relu -> hs (fp32, LDS), stage W2 chunk, V-GEMM, atomic lt ----
    float* hs  = (float*)smem;                 // [32][68]
    float* w2s = (float*)(smem + 8704);        // [64][22] + pad (1416 floats)
    {
        const int mrow = wm * 16 + ((lane >> 4) << 2);
        #pragma unroll
        for (int ni = 0; ni < 2; ++ni) {
            int col = wn * 32 + ni * 16 + (lane & 15);
            float bias = b1[f0 + col];
            #pragma unroll
            for (int r = 0; r < 4; ++r)
                hs[(mrow + r) * 68 + col] = fmaxf(acc[ni][r] + bias, 0.f);
        }
    }
    for (int i = tid; i < 64 * V; i += 256) w2s[i] = W2[(size_t)f0 * V + i];
    __syncthreads();

    {
        const int row = tid >> 3;
        const int vb = (tid & 7) * 3;
        float a0 = 0.f, a1 = 0.f, a2 = 0.f;
        #pragma unroll 8
        for (int f = 0; f < 64; ++f) {
            float h = hs[row * 68 + f];
            const float* w = &w2s[f * V + vb];
            a0 = fmaf(h, w[0], a0);
            a1 = fmaf(h, w[1], a1);
            a2 = fmaf(h, w[2], a2);
        }
        float* ltr = lt + (size_t)(m0 + row) * V + vb;
        atomicAdd(ltr, a0);
        if (vb + 1 < V) atomicAdd(ltr + 1, a1);
        if (vb + 2 < V) atomicAdd(ltr + 2, a2);
    }
#undef LOADT
#undef WRITET
#undef COMPUTET
}

// =============== K3: scatter with constraint mask ===============
__global__ __launch_bounds__(256) void scatter_out(
    const int* __restrict__ tokens, const float* __restrict__ lt,
    const int* __restrict__ n_dig, float* __restrict__ out)
{
    int idx = blockIdx.x * blockDim.x + threadIdx.x;
    if (idx >= NB * NS * V) return;
    int v = idx % V;
    int bs = idx / V;
    int s = bs % NS;
    int b = bs / NS;
    int tok = tokens[b * NS + s];
    float nd = (float)n_dig[b];
    float nn = (float)(NS - 1) - nd;
    float dd = ((0x3FE007 >> v) & 1) ? 1.f : 0.f;
    float dn = ((0x001007 >> v) & 1) ? 1.f : 0.f;
    float mask = nd * dd + nn * dn;
    out[idx] = lt[(b * V + tok) * V + v] - 0.5f * mask;
}

extern "C" void kernel_launch(void* const* d_in, const int* in_sizes, int n_in,
                              void* d_out, int out_size, void* d_ws, size_t ws_size,
                              hipStream_t stream) {
    const int*   tokens = (const int*)d_in[0];
    const float* z      = (const float*)d_in[1];
    const float* emb    = (const float*)d_in[2];
    const float* W1     = (const float*)d_in[3];
    const float* b1     = (const float*)d_in[4];
    const float* W2     = (const float*)d_in[5];
    const float* b2     = (const float*)d_in[6];
    float* out = (float*)d_out;

    char* ws = (char*)d_ws;
    ushort_t* W1T = (ushort_t*)ws;                 // 2048*512*2 = 2097152 B
    ushort_t* X   = (ushort_t*)(ws + 2097152);     // 704*512*2  = 720896 B
    float*    lt  = (float*)(ws + 2818048);        // 704*22*4   = 61952 B
    int*      n_dig = (int*)(ws + 2880000);        // 128 B

    prep_kernel<<<525, 256, 0, stream>>>(tokens, z, emb, W1, b2, W1T, X, lt, n_dig);
    gemm_fused<<<dim3(22, 32), 256, 0, stream>>>(X, W1T, b1, W2, lt);
    scatter_out<<<1408, 256, 0, stream>>>(tokens, lt, n_dig, out);
}